// Round 7
// baseline (197.620 us; speedup 1.0000x reference)
//
#include <hip/hip_runtime.h>
#include <hip/hip_bf16.h>
#include <cstdint>

// Problem (all inputs/outputs fp32):
//   out[8192][2048] = X[8192][2048] @ Weff[2048][2048]
//   Weff[k][n] = W[k][n] + SCALE * sum_r A[k][r]*Bk[r][n], SCALE = 4/4 = 1.0
//
// Pipeline (2 launches):
//   prep_all: [blocks 0..8191] fp32 X -> bf16 Xb (d_ws)
//             [blocks 8192..9215] fp32 (W + A@Bk)^T -> bf16 Wt [N][K]
//   gemm_8ph: 256x256 tile, BK=64, 8 waves (2Mx4N), rotated 8-phase,
//             ISSUE-INTERLEAVED {2 MFMA, 1 ds_read} chunks (R7).
//
// R6 post-mortem: setprio intrinsics are side-effecting -> LLVM cannot move
// the phase's ds_reads between the MFMAs; per-wave in-order issue serializes
// LDS pipe vs MFMA pipe (LDS idle ~620cyc during MFMA issue, then reads
// drain with MFMA idle). R7: hand-interleave each phase as {2 MFMA, 1 read}
// chunks with sched_barrier(0) fences; WAR-safe by construction (each frag
// re-read placed right after its last consuming MFMA; sources latch at MFMA
// issue). setprio wraps the whole cluster. Stages issued at phase start.
//
// Rotated ledger (UNCHANGED from R4/R6, correctness-proven twice; stage
// slots s1..s8 load tiles 2j+2 (kn0), 2j+3 (kn1); 2 loads each):
//   P2:MMA q00/b0 rd B1->b1 | P3:q01/b1 rd A1->a st s1 | P4:q11/b1 st s2 |
//   P5:q10/b0 VMW(6) rd A0,B0/buf1 st s3 | P6:q00/b0 rd B1 st s4 |
//   P7:q01/b1 VMW(8) rd A1 st s5,s6 | P8:q11/b1 st s7 |
//   P1':q10/b0 VMW(6) rd A0,B0/buf0 st s8
// Load-FIFO (2 loads per stage): enter P2 with {s5..s8}(j-1)=8 outstanding.
//   VMW(6)@P5: 12 outstanding -> drains s5..s7(j-1), publishes P5/P6 reads.
//   VMW(8)@P7: drains s8(j-1), publishes P7 read. VMW(6)@P1': drains
//   s1..s4(j), publishes P1'/P2'/P3' reads. WAR: regions restaged >=2
//   phases after last read (single barrier/phase happens-before chain).
// Peeled last iter: VMW(4)@P5, VMW(0)@P6, stores by quadrant P6..P9, no
// vm-waits after stores begin (stores count in vmcnt).
// Round-4 lesson kept: do NOT read fp32 X inside the gemm K-loop.
// R5 lesson: ~110us of total is harness-side constant; two-kernel path wins.

using bf16 = __hip_bfloat16;
typedef __attribute__((ext_vector_type(8))) __bf16 bf16x8;
typedef __attribute__((ext_vector_type(4))) float f32x4;

constexpr int Mdim = 8192;   // B*S
constexpr int Ndim = 2048;   // NH*HD
constexpr int Kdim = 2048;   // H
constexpr float SCALE = 1.0f;  // ALPHA/RANK = 4/4

constexpr int BM = 256, BN = 256, BK = 64;
constexpr int NT2 = Kdim / (2 * BK);                   // 16 iterations
constexpr int CVT_BLOCKS = (Mdim * Kdim) / (256 * 8);  // 8192
constexpr int PREP_BLOCKS = (Ndim / 64) * (Kdim / 64); // 1024

__device__ __forceinline__ void gload_lds16(const void* g, void* l) {
  __builtin_amdgcn_global_load_lds(
      (const __attribute__((address_space(1))) uint32_t*)g,
      (__attribute__((address_space(3))) uint32_t*)l,
      16, 0, 0);
}

__device__ __forceinline__ uint16_t f2bf(float f) {
  return __bfloat16_as_ushort(__float2bfloat16(f));
}

// ------------- prep_all: cvt_x (blocks<8192) + Weff^T build --------------
__global__ void prep_all(const float* __restrict__ X,
                         const float* __restrict__ W,
                         const float* __restrict__ A,
                         const float* __restrict__ Bk,
                         uint16_t* __restrict__ Xb,
                         uint16_t* __restrict__ Wt) {
  __shared__ float tile[64][65];  // used by prep part only (+1 pad)

  if (blockIdx.x < CVT_BLOCKS) {
    // ---- fp32 -> bf16, 8 elems/thread, float4 loads ----
    const int i = blockIdx.x * blockDim.x + threadIdx.x;
    const float4* Xv = (const float4*)X;
    float4 a = Xv[i * 2 + 0];
    float4 b = Xv[i * 2 + 1];
    uint16_t o[8];
    o[0] = f2bf(a.x); o[1] = f2bf(a.y); o[2] = f2bf(a.z); o[3] = f2bf(a.w);
    o[4] = f2bf(b.x); o[5] = f2bf(b.y); o[6] = f2bf(b.z); o[7] = f2bf(b.w);
    *reinterpret_cast<uint4*>(Xb + (size_t)i * 8) = *reinterpret_cast<uint4*>(o);
  } else {
    // ---- Weff^T = (W + A@Bk)^T, [N][K] bf16 ----
    const int pid = blockIdx.x - CVT_BLOCKS;       // 0..1023
    const int tx = threadIdx.x & 63;
    const int ty = threadIdx.x >> 6;
    const int n0 = (pid & 31) * 64, k0 = (pid >> 5) * 64;

    const int n = n0 + tx;
    const float b0 = Bk[0 * Ndim + n];
    const float b1 = Bk[1 * Ndim + n];
    const float b2 = Bk[2 * Ndim + n];
    const float b3 = Bk[3 * Ndim + n];

    for (int i = ty; i < 64; i += 4) {
      const int k = k0 + i;
      float w = W[(size_t)k * Ndim + n];
      w += SCALE * (A[k * 4 + 0] * b0 + A[k * 4 + 1] * b1 +
                    A[k * 4 + 2] * b2 + A[k * 4 + 3] * b3);
      tile[tx][i] = w;                       // transposed into LDS
    }
    __syncthreads();
    for (int i = ty; i < 64; i += 4) {
      Wt[(size_t)(n0 + i) * Kdim + (k0 + tx)] = f2bf(tile[i][tx]);
    }
  }
}

// ---------------- main GEMM: C = Xb @ Weff (Wt is Weff^T, K-major) --------
#define FENCE() asm volatile("" ::: "memory")
#define VMW(N)  asm volatile("s_waitcnt vmcnt(" #N ")" ::: "memory")
#define PH()                                                                   \
  do {                                                                         \
    FENCE();                                                                   \
    __builtin_amdgcn_s_barrier();                                              \
    FENCE();                                                                   \
  } while (0)
#define SB() __builtin_amdgcn_sched_barrier(0)

__global__ __launch_bounds__(512, 2) void gemm_8ph(
    const uint16_t* __restrict__ X, const uint16_t* __restrict__ Wt,
    float* __restrict__ out) {
  // LDS: [A0 | B0 | A1 | B1], 16384 uint16 each = 128 KiB total.
  __shared__ uint16_t lds[65536];

  const int t = threadIdx.x;
  const int wave = t >> 6, lane = t & 63;
  const int wm = wave >> 2, wn = wave & 3;   // 2 x 4 wave grid
  const int l15 = lane & 15, kg = lane >> 4;
  const int sw = l15 & 7;

  // Bijective XCD patch swizzle: 256 blocks, 8 XCDs x 32 blocks.
  const int lid = blockIdx.x;                 // 0..255
  const int xcd = lid & 7, loc = lid >> 3;    // loc 0..31
  const int by = xcd * 4 + (loc & 3);         // 0..31
  const int bx = loc >> 2;                    // 0..7
  const int m0 = by * BM, n0 = bx * BN;

  const uint16_t* Ag = X + (size_t)m0 * Kdim;
  const uint16_t* Bg = Wt + (size_t)n0 * Kdim;

  // staging: slot = 8 rows x 64 cols (1 KB); wave w owns slots {2w,2w+1}.
  // Source chunk col XOR-swizzled -> linear LDS holds phys p = c ^ (row&7).
  const int r8 = lane >> 3;
  const int gc = (lane & 7) ^ r8;
  const int slot0 = wave * 2, slot1 = slot0 + 1;
  const size_t go0 = (size_t)(slot0 * 8 + r8) * Kdim + gc * 8;
  const size_t go1 = (size_t)(slot1 * 8 + r8) * Kdim + gc * 8;

  // per-lane LDS element offsets for frag reads (per k-step s2)
  int aE[2], bE[2];
#pragma unroll
  for (int s2 = 0; s2 < 2; ++s2) {
    const int p = (s2 * 4 + kg) ^ sw;
    aE[s2] = (wm * 64 + l15) * 64 + p * 8;
    bE[s2] = (wn * 32 + l15) * 64 + p * 8;
  }

#define STAGE_A(buf, h, kt)                                                    \
  do {                                                                         \
    gload_lds16(Ag + go0 + (size_t)(h) * 128 * Kdim + (kt),                    \
                &lds[(buf) * 32768 + (h) * 8192 + slot0 * 512]);               \
    gload_lds16(Ag + go1 + (size_t)(h) * 128 * Kdim + (kt),                    \
                &lds[(buf) * 32768 + (h) * 8192 + slot1 * 512]);               \
  } while (0)
#define STAGE_B(buf, h, kt)                                                    \
  do {                                                                         \
    gload_lds16(Bg + go0 + (size_t)(h) * 128 * Kdim + (kt),                    \
                &lds[(buf) * 32768 + 16384 + (h) * 8192 + slot0 * 512]);       \
    gload_lds16(Bg + go1 + (size_t)(h) * 128 * Kdim + (kt),                    \
                &lds[(buf) * 32768 + 16384 + (h) * 8192 + slot1 * 512]);       \
  } while (0)

  bf16x8 a[4][2], b0[2][2], b1[2][2];
  f32x4 acc[8][4] = {};

  // ---- single-op building blocks ----
#define MFMA1(QM, QN, ii, jj, s2, barr)                                        \
  acc[(QM) * 4 + (ii)][(QN) * 2 + (jj)] =                                      \
      __builtin_amdgcn_mfma_f32_16x16x32_bf16(                                 \
          a[ii][s2], barr[jj][s2], acc[(QM) * 4 + (ii)][(QN) * 2 + (jj)],      \
          0, 0, 0)
#define RD_A1(buf, h, ii, s2)                                                  \
  a[ii][s2] = *reinterpret_cast<const bf16x8*>(                                \
      &lds[(buf) * 32768 + (h) * 8192 + (ii) * 1024 + aE[s2]])
#define RD_B1(buf, h, jj, s2, dst)                                             \
  dst[jj][s2] = *reinterpret_cast<const bf16x8*>(                              \
      &lds[(buf) * 32768 + 16384 + (h) * 8192 + (jj) * 1024 + bE[s2]])
#define READ_A(QM, buf)                                                        \
  do {                                                                         \
    RD_A1(buf, QM, 0, 0); RD_A1(buf, QM, 1, 0);                                \
    RD_A1(buf, QM, 2, 0); RD_A1(buf, QM, 3, 0);                                \
    RD_A1(buf, QM, 0, 1); RD_A1(buf, QM, 1, 1);                                \
    RD_A1(buf, QM, 2, 1); RD_A1(buf, QM, 3, 1);                                \
  } while (0)
#define READ_B(QN, buf, dst)                                                   \
  do {                                                                         \
    RD_B1(buf, QN, 0, 0, dst); RD_B1(buf, QN, 1, 0, dst);                      \
    RD_B1(buf, QN, 0, 1, dst); RD_B1(buf, QN, 1, 1, dst);                      \
  } while (0)

  // ---- interleaved phase clusters (R7) ----
  // Pure MMA, no reads (P4/P8).
#define PH_MMA(QM, QN, barr)                                                   \
  do {                                                                         \
    __builtin_amdgcn_s_setprio(1);                                             \
    MFMA1(QM,QN,0,0,0,barr); MFMA1(QM,QN,0,1,0,barr);                          \
    MFMA1(QM,QN,1,0,0,barr); MFMA1(QM,QN,1,1,0,barr);                          \
    MFMA1(QM,QN,2,0,0,barr); MFMA1(QM,QN,2,1,0,barr);                          \
    MFMA1(QM,QN,3,0,0,barr); MFMA1(QM,QN,3,1,0,barr);                          \
    MFMA1(QM,QN,0,0,1,barr); MFMA1(QM,QN,0,1,1,barr);                          \
    MFMA1(QM,QN,1,0,1,barr); MFMA1(QM,QN,1,1,1,barr);                          \
    MFMA1(QM,QN,2,0,1,barr); MFMA1(QM,QN,2,1,1,barr);                          \
    MFMA1(QM,QN,3,0,1,barr); MFMA1(QM,QN,3,1,1,barr);                          \
    __builtin_amdgcn_s_setprio(0);                                             \
  } while (0)
  // MMA + 4 B-reads into the OTHER b-buffer (no WAR): P2/P6.
#define PH_MMA_RDB(QM, QN, barr, rbuf, rh, rdst)                               \
  do {                                                                         \
    __builtin_amdgcn_s_setprio(1);                                             \
    MFMA1(QM,QN,0,0,0,barr); MFMA1(QM,QN,0,1,0,barr);                          \
    RD_B1(rbuf,rh,0,0,rdst); SB();                                             \
    MFMA1(QM,QN,1,0,0,barr); MFMA1(QM,QN,1,1,0,barr);                          \
    RD_B1(rbuf,rh,1,0,rdst); SB();                                             \
    MFMA1(QM,QN,2,0,0,barr); MFMA1(QM,QN,2,1,0,barr);                          \
    RD_B1(rbuf,rh,0,1,rdst); SB();                                             \
    MFMA1(QM,QN,3,0,0,barr); MFMA1(QM,QN,3,1,0,barr);                          \
    RD_B1(rbuf,rh,1,1,rdst); SB();                                             \
    MFMA1(QM,QN,0,0,1,barr); MFMA1(QM,QN,0,1,1,barr);                          \
    MFMA1(QM,QN,1,0,1,barr); MFMA1(QM,QN,1,1,1,barr);                          \
    MFMA1(QM,QN,2,0,1,barr); MFMA1(QM,QN,2,1,1,barr);                          \
    MFMA1(QM,QN,3,0,1,barr); MFMA1(QM,QN,3,1,1,barr);                          \
    __builtin_amdgcn_s_setprio(0);                                             \
  } while (0)
  // MMA + 8 A-reads overwriting a[] (WAR-safe: a[ii][s2] re-read right
  // after its two consuming MFMAs): P3/P7.
#define PH_MMA_RDA(QM, QN, barr, rbuf, rh)                                     \
  do {                                                                         \
    __builtin_amdgcn_s_setprio(1);                                             \
    MFMA1(QM,QN,0,0,0,barr); MFMA1(QM,QN,0,1,0,barr); RD_A1(rbuf,rh,0,0); SB();\
    MFMA1(QM,QN,1,0,0,barr); MFMA1(QM,QN,1,1,0,barr); RD_A1(rbuf,rh,1,0); SB();\
    MFMA1(QM,QN,2,0,0,barr); MFMA1(QM,QN,2,1,0,barr); RD_A1(rbuf,rh,2,0); SB();\
    MFMA1(QM,QN,3,0,0,barr); MFMA1(QM,QN,3,1,0,barr); RD_A1(rbuf,rh,3,0); SB();\
    MFMA1(QM,QN,0,0,1,barr); MFMA1(QM,QN,0,1,1,barr); RD_A1(rbuf,rh,0,1); SB();\
    MFMA1(QM,QN,1,0,1,barr); MFMA1(QM,QN,1,1,1,barr); RD_A1(rbuf,rh,1,1); SB();\
    MFMA1(QM,QN,2,0,1,barr); MFMA1(QM,QN,2,1,1,barr); RD_A1(rbuf,rh,2,1); SB();\
    MFMA1(QM,QN,3,0,1,barr); MFMA1(QM,QN,3,1,1,barr); RD_A1(rbuf,rh,3,1); SB();\
    __builtin_amdgcn_s_setprio(0);                                             \
  } while (0)
  // MMA q(1,0) consuming a,b0 + 12 reads refilling a (A0-half, rbuf) and b0
  // (B0-half, rbuf). b0[jj][s2] re-read only after the full ii-sweep of its
  // s2 block (its last consumer is ii=3): P5/P1'.
#define PH_MMA_RDAB(rbuf)                                                      \
  do {                                                                         \
    __builtin_amdgcn_s_setprio(1);                                             \
    MFMA1(1,0,0,0,0,b0); MFMA1(1,0,0,1,0,b0); RD_A1(rbuf,0,0,0); SB();         \
    MFMA1(1,0,1,0,0,b0); MFMA1(1,0,1,1,0,b0); RD_A1(rbuf,0,1,0); SB();         \
    MFMA1(1,0,2,0,0,b0); MFMA1(1,0,2,1,0,b0); RD_A1(rbuf,0,2,0); SB();         \
    MFMA1(1,0,3,0,0,b0); MFMA1(1,0,3,1,0,b0); RD_A1(rbuf,0,3,0); SB();         \
    RD_B1(rbuf,0,0,0,b0); RD_B1(rbuf,0,1,0,b0); SB();                          \
    MFMA1(1,0,0,0,1,b0); MFMA1(1,0,0,1,1,b0); RD_A1(rbuf,0,0,1); SB();         \
    MFMA1(1,0,1,0,1,b0); MFMA1(1,0,1,1,1,b0); RD_A1(rbuf,0,1,1); SB();         \
    MFMA1(1,0,2,0,1,b0); MFMA1(1,0,2,1,1,b0); RD_A1(rbuf,0,2,1); SB();         \
    MFMA1(1,0,3,0,1,b0); MFMA1(1,0,3,1,1,b0); RD_A1(rbuf,0,3,1); SB();         \
    RD_B1(rbuf,0,0,1,b0); RD_B1(rbuf,0,1,1,b0); SB();                          \
    __builtin_amdgcn_s_setprio(0);                                             \
  } while (0)

// store one 128x128 output quadrant (this wave's 64x32 piece of it)
#define STORE_Q(QM, QN)                                                        \
  do {                                                                         \
    _Pragma("unroll") for (int ii = 0; ii < 4; ++ii) {                         \
      const int mb = m0 + (QM) * 128 + wm * 64 + ii * 16 + kg * 4;             \
      _Pragma("unroll") for (int jj = 0; jj < 2; ++jj) {                       \
        const int n = n0 + (QN) * 128 + wn * 32 + jj * 16 + l15;               \
        _Pragma("unroll") for (int r = 0; r < 4; ++r)                          \
            out[(size_t)(mb + r) * Ndim + n] =                                 \
                acc[(QM) * 4 + ii][(QN) * 2 + jj][r];                          \
      }                                                                        \
    }                                                                          \
  } while (0)

  // ---- prologue: buf0{B0,A0,B1,A1}, buf1{B0,A0,B1} (FIFO order matters) ----
  STAGE_B(0, 0, 0); STAGE_A(0, 0, 0); STAGE_B(0, 1, 0); STAGE_A(0, 1, 0);
  FENCE();
  STAGE_B(1, 0, BK); STAGE_A(1, 0, BK); STAGE_B(1, 1, BK);
  FENCE();
  // "P1(0)": publish buf0; read A0,B0; stage s8(-1)=buf1.A1. No MMA.
  VMW(6); PH();
  READ_A(0, 0); READ_B(0, 0, b0);
  STAGE_A(1, 1, BK);

  // ---- steady loop: full iterations j = 0 .. NT2-2 ----
#pragma unroll 1
  for (int j = 0; j < NT2 - 1; ++j) {
    const int kn0 = j * 128 + 128;   // tile 2j+2 -> buf0
    const int kn1 = j * 128 + 192;   // tile 2j+3 -> buf1

    // P2: MMA q00 (a=A0,b0) || read B1-buf0 -> b1
    PH(); PH_MMA_RDB(0, 0, b0, 0, 1, b1);
    // P3: MMA q01 (a=A0,b1) || read A1-buf0 -> a      | stage s1
    PH(); STAGE_B(0, 0, kn0); PH_MMA_RDA(0, 1, b1, 0, 1);
    // P4: MMA q11 (a=A1,b1)                            | stage s2
    PH(); STAGE_A(0, 0, kn0); PH_MMA(1, 1, b1);
    // P5: MMA q10 (a=A1,b0) || read A0,B0-buf1 -> a,b0 | stage s3
    VMW(6); PH(); STAGE_B(0, 1, kn0); PH_MMA_RDAB(1);
    // P6: MMA q00 buf1 || read B1-buf1 -> b1           | stage s4
    PH(); STAGE_A(0, 1, kn0); PH_MMA_RDB(0, 0, b0, 1, 1, b1);
    // P7: MMA q01 || read A1-buf1 -> a                 | stage s5,s6
    VMW(8); PH(); STAGE_B(1, 0, kn1); STAGE_A(1, 0, kn1);
    PH_MMA_RDA(0, 1, b1, 1, 1);
    // P8: MMA q11                                      | stage s7
    PH(); STAGE_B(1, 1, kn1); PH_MMA(1, 1, b1);
    // P1': MMA q10 || read A0,B0-buf0 -> a,b0          | stage s8
    VMW(6); PH(); STAGE_A(1, 1, kn1); PH_MMA_RDAB(0);
  }

  // ---- peeled last iteration: no staging; stores overlap final phases ----
  PH(); PH_MMA_RDB(0, 0, b0, 0, 1, b1);
  PH(); PH_MMA_RDA(0, 1, b1, 0, 1);
  PH(); PH_MMA(1, 1, b1);
  // P5: publish buf1.{B0,A0} (s5,s6 issued 6 phases ago -> free)
  VMW(4); PH(); PH_MMA_RDAB(1);
  // P6: drain s7,s8; stores begin, no vm-waits after this point
  VMW(0); PH(); PH_MMA_RDB(0, 0, b0, 1, 1, b1); STORE_Q(0, 0);
  PH(); PH_MMA_RDA(0, 1, b1, 1, 1); STORE_Q(0, 1);
  PH(); PH_MMA(1, 1, b1); STORE_Q(1, 1);
  PH(); PH_MMA(1, 0, b0); STORE_Q(1, 0);

#undef STAGE_A
#undef STAGE_B
#undef MFMA1
#undef RD_A1
#undef RD_B1
#undef READ_A
#undef READ_B
#undef PH_MMA
#undef PH_MMA_RDB
#undef PH_MMA_RDA
#undef PH_MMA_RDAB
#undef STORE_Q
}

extern "C" void kernel_launch(void* const* d_in, const int* in_sizes, int n_in,
                              void* d_out, int out_size, void* d_ws, size_t ws_size,
                              hipStream_t stream) {
  const float* x  = (const float*)d_in[0];  // [4,2048,2048]
  const float* W  = (const float*)d_in[1];  // [2048,16,128]
  const float* A  = (const float*)d_in[2];  // [2048,4]
  const float* Bk = (const float*)d_in[3];  // [4,16,128]
  float* out = (float*)d_out;               // [4,2048,16,128] fp32

  uint16_t* Xb = (uint16_t*)d_ws;                                     // 32 MB
  uint16_t* Wt = (uint16_t*)((char*)d_ws + (size_t)Mdim * Kdim * 2);  // 8 MB

  // fused: X fp32->bf16  +  Weff^T build
  prep_all<<<CVT_BLOCKS + PREP_BLOCKS, 256, 0, stream>>>(x, W, A, Bk, Xb, Wt);

  // main GEMM: 256 blocks (1/CU), 512 threads, interleaved rotated 8-phase
  gemm_8ph<<<(Mdim / BM) * (Ndim / BN), 512, 0, stream>>>(Xb, Wt, out);
}